// Round 13
// baseline (771.592 us; speedup 1.0000x reference)
//
#include <hip/hip_runtime.h>
#include <hip/hip_cooperative_groups.h>
#include <stdint.h>

namespace cg = cooperative_groups;

// GCN forward, collapsed to scalar form (W1:[1,16], W2:[16,1] are rank-1).
// R13: ENTIRE pipeline in ONE cooperative kernel with grid.sync() phases.
// R6-R12 evidence: every edge-scale pass costs ~40-50us regardless of inner
// structure (occupancy/MLP/LDS-gather/async-fill all invariant; all pipes
// idle) and 10 dispatches carry ~8-10us launch overhead each. So: fuse.
// Phases: cnt | scanA | scanB | part(tile-sort) | deg | node1 | scat(y) |
// node2 | scat(z2) | final, separated by grid.sync() (agent-scope fences
// writeback/invalidate per-XCD L2 on gfx950).
// No global atomics anywhere (R2-R4: gfx950 global atomic RMW is memory-side
// ~20 G/s, WRITE_SIZE=E*32B regardless of privatization/scope).
// Dropout = JAX partitionable threefry: split k_i=E(key,(0,i)) both words;
// bits(j) = o0^o1 of E(k,(0,j)); u=(bits>>9|0x3f800000)-1; keep iff u<0.4.
// Requires NCELL <= 640 (N <= ~131072 with these RANGE/QRANGE).

#define KEEP_P 0.4f
#define RANGE 2048
#define SHIFT 11
#define MASK 2047
#define QRANGE 8192
#define QSHIFT 13
#define QMASK 8191
#define NCELLP 640
#define TILE 8192
#define TILE4 (TILE / 4)
#define DSJ 10
#define GMAX 512

union __align__(16) Shared {
  struct { float cache[QRANGE]; float bins[RANGE]; } sc;            // 40 KB
  struct {
    unsigned stage[TILE];                                           // 32 KB
    unsigned short cellid[TILE];                                    // 16 KB
    unsigned hist[NCELLP], off[NCELLP], tscan[NCELLP];
    unsigned tbase[NCELLP], blkcur[NCELLP];                         // 12.8 KB
    unsigned ssum[256];                                             // 1 KB
  } pt;
  struct { unsigned hist[NCELLP]; } ct;
  struct { unsigned ssum[256]; } sn;
  struct { unsigned bins[RANGE / 2]; } dg;
};

struct Par {
  const int *src, *dst;
  const float *x, *W1, *b1, *W2, *b2;
  float* out;
  unsigned *counts, *bases, *total, *cellst, *rec;
  float* part;
  unsigned short* degpart;
  float *dinv, *y, *z2;
  int N, E, e4, NB, NQ, NCELL;
  unsigned k1a, k1b, k2a, k2b;
};

__host__ __device__ inline unsigned rotl32(unsigned v, int s) {
  return (v << s) | (v >> (32 - s));
}

__host__ __device__ inline void threefry2x32(unsigned key0, unsigned key1,
                                             unsigned x0, unsigned x1,
                                             unsigned& o0, unsigned& o1) {
  unsigned ks0 = key0, ks1 = key1, ks2 = key0 ^ key1 ^ 0x1BD11BDAu;
  unsigned v0 = x0 + ks0, v1 = x1 + ks1;
#define TF_R(r) { v0 += v1; v1 = rotl32(v1, r); v1 ^= v0; }
  TF_R(13) TF_R(15) TF_R(26) TF_R(6)
  v0 += ks1; v1 += ks2 + 1u;
  TF_R(17) TF_R(29) TF_R(16) TF_R(24)
  v0 += ks2; v1 += ks0 + 2u;
  TF_R(13) TF_R(15) TF_R(26) TF_R(6)
  v0 += ks0; v1 += ks1 + 3u;
  TF_R(17) TF_R(29) TF_R(16) TF_R(24)
  v0 += ks1; v1 += ks2 + 4u;
  TF_R(13) TF_R(15) TF_R(26) TF_R(6)
  v0 += ks2; v1 += ks0 + 5u;
#undef TF_R
  o0 = v0; o1 = v1;
}

__device__ inline float u01_from_bits(unsigned bits) {
  return __uint_as_float((bits >> 9) | 0x3f800000u) - 1.0f;
}

// ---- scatter phase: per half-cell, LDS val cache + LDS bins ----------------
__device__ void scat_phase(const Par& p, Shared& u, const float* val) {
  const int tid = threadIdx.x, w = tid >> 6, lane = tid & 63;
  const int items = 2 * p.NCELL;
  for (int m = blockIdx.x; m < items; m += gridDim.x) {
    const int q = m / (2 * p.NB);
    const int rem = m - q * 2 * p.NB;
    const int pp = rem >> 1, h = rem & 1;
    const int g0 = q * QRANGE;
    const int lim = min(QRANGE, p.N - g0);
    __syncthreads();  // protect cache/bins from previous item's readers
    if (lim == QRANGE) {
      const float* gsrc = val + g0 + (w << 11) + (lane << 2);
      float* ldst = u.sc.cache + (w << 11);
#pragma unroll
      for (int k = 0; k < 8; ++k) {
        __builtin_amdgcn_global_load_lds(
            (const __attribute__((address_space(1))) void*)(gsrc + (k << 8)),
            (__attribute__((address_space(3))) void*)(ldst + (k << 8)),
            16, 0, 0);
      }
    } else {
      for (int i = tid; i < lim; i += 256) u.sc.cache[i] = val[g0 + i];
    }
    for (int i = tid; i < RANGE; i += 256) u.sc.bins[i] = 0.0f;
    __syncthreads();  // drains vmcnt before barrier
    const int s0c = (int)p.cellst[pp * p.NQ + q];
    const int s1c = (int)p.cellst[pp * p.NQ + q + 1];
    const int mid = s0c + ((s1c - s0c) >> 1);
    const int a = h ? mid : s0c;
    const int b = h ? s1c : mid;
    int i = a + tid;
    for (; i + 768 < b; i += 1024) {
      unsigned v0 = p.rec[i], v1 = p.rec[i + 256];
      unsigned v2 = p.rec[i + 512], v3 = p.rec[i + 768];
      float f0 = u.sc.cache[v0 >> SHIFT], f1 = u.sc.cache[v1 >> SHIFT];
      float f2 = u.sc.cache[v2 >> SHIFT], f3 = u.sc.cache[v3 >> SHIFT];
      atomicAdd(&u.sc.bins[v0 & MASK], f0);
      atomicAdd(&u.sc.bins[v1 & MASK], f1);
      atomicAdd(&u.sc.bins[v2 & MASK], f2);
      atomicAdd(&u.sc.bins[v3 & MASK], f3);
    }
    for (; i < b; i += 256) {
      unsigned v = p.rec[i];
      atomicAdd(&u.sc.bins[v & MASK], u.sc.cache[v >> SHIFT]);
    }
    __syncthreads();
    float* my = p.part + (size_t)m * RANGE;
    for (int i2 = tid; i2 < RANGE; i2 += 256) my[i2] = u.sc.bins[i2];
  }
}

__global__ __launch_bounds__(256) void k_all(Par p) {
  cg::grid_group grid = cg::this_grid();
  __shared__ Shared u;
  const int tid = threadIdx.x;
  const int g = blockIdx.x;
  const int G = gridDim.x;
  const int4* d4 = reinterpret_cast<const int4*>(p.dst);
  const int4* s4 = reinterpret_cast<const int4*>(p.src);

  // ===== Phase 1: per-block cell histogram =====
  {
    for (int c = tid; c < p.NCELL; c += 256) u.ct.hist[c] = 0u;
    __syncthreads();
    const int chunk = (p.e4 + G - 1) / G;
    const int j0 = g * chunk, j1 = min(j0 + chunk, p.e4);
    for (int j = j0 + tid; j < j1; j += 256) {
      int4 d = d4[j]; int4 s = s4[j];
      atomicAdd(&u.ct.hist[((unsigned)d.x >> SHIFT) * p.NQ + ((unsigned)s.x >> QSHIFT)], 1u);
      atomicAdd(&u.ct.hist[((unsigned)d.y >> SHIFT) * p.NQ + ((unsigned)s.y >> QSHIFT)], 1u);
      atomicAdd(&u.ct.hist[((unsigned)d.z >> SHIFT) * p.NQ + ((unsigned)s.z >> QSHIFT)], 1u);
      atomicAdd(&u.ct.hist[((unsigned)d.w >> SHIFT) * p.NQ + ((unsigned)s.w >> QSHIFT)], 1u);
    }
    if (g == 0) {  // tail when E%4 != 0 (dead for E=6.4M)
      for (int t = p.e4 * 4 + tid; t < p.E; t += 256)
        atomicAdd(&u.ct.hist[((unsigned)p.dst[t] >> SHIFT) * p.NQ +
                             ((unsigned)p.src[t] >> QSHIFT)], 1u);
    }
    __syncthreads();
    // bucket-major layout: counts[c*G + b] -> coalesced scan reads
    for (int c = tid; c < p.NCELL; c += 256)
      p.counts[(size_t)c * G + g] = u.ct.hist[c];
  }
  grid.sync();

  // ===== Phase 2: per-cell exclusive scan over blocks =====
  {
    const int per = (G + 255) / 256;  // <= 2 for G<=512
    for (int c = g; c < p.NCELL; c += G) {
      unsigned l[4]; unsigned s = 0;
      for (int k = 0; k < per; ++k) {
        int b = tid * per + k;
        unsigned v = (b < G) ? p.counts[(size_t)c * G + b] : 0u;
        l[k] = s; s += v;
      }
      u.sn.ssum[tid] = s;
      __syncthreads();
      for (int ofs = 1; ofs < 256; ofs <<= 1) {
        unsigned v = (tid >= ofs) ? u.sn.ssum[tid - ofs] : 0u;
        __syncthreads();
        u.sn.ssum[tid] += v;
        __syncthreads();
      }
      unsigned excl = u.sn.ssum[tid] - s;
      for (int k = 0; k < per; ++k) {
        int b = tid * per + k;
        if (b < G) p.bases[(size_t)c * G + b] = excl + l[k];
      }
      if (tid == 255) p.total[c] = u.sn.ssum[255];
      __syncthreads();
    }
  }
  grid.sync();

  // ===== Phase 3: exclusive scan over cells (block 0) =====
  if (g == 0) {
    const int K = (p.NCELL + 255) / 256;  // <= 3
    unsigned l[4]; unsigned s = 0;
    for (int k = 0; k < K; ++k) {
      int c = tid * K + k;
      unsigned v = (c < p.NCELL) ? p.total[c] : 0u;
      l[k] = s; s += v;
    }
    u.sn.ssum[tid] = s;
    __syncthreads();
    for (int ofs = 1; ofs < 256; ofs <<= 1) {
      unsigned v = (tid >= ofs) ? u.sn.ssum[tid - ofs] : 0u;
      __syncthreads();
      u.sn.ssum[tid] += v;
      __syncthreads();
    }
    unsigned excl = u.sn.ssum[tid] - s;
    for (int k = 0; k < K; ++k) {
      int c = tid * K + k;
      if (c < p.NCELL) p.cellst[c] = excl + l[k];
    }
    if (tid == 255) p.cellst[p.NCELL] = (unsigned)p.E;
  }
  grid.sync();

  // ===== Phase 4: tile-sorted partition to exact cell positions =====
  {
    for (int c = tid; c < p.NCELL; c += 256)
      u.pt.blkcur[c] = p.cellst[c] + p.bases[(size_t)c * G + g];
    const int chunk = (p.e4 + G - 1) / G;
    const int j0 = g * chunk, j1 = min(j0 + chunk, p.e4);
    const int K = (p.NCELL + 255) / 256;  // <= 3
    for (int t0 = j0; t0 < j1; t0 += TILE4) {
      __syncthreads();
      for (int c = tid; c < p.NCELL; c += 256) u.pt.hist[c] = 0u;
      __syncthreads();
      const int tcnt = min(TILE4, j1 - t0);
      for (int jj = tid; jj < tcnt; jj += 256) {
        int4 d = d4[t0 + jj]; int4 s = s4[t0 + jj];
        atomicAdd(&u.pt.hist[((unsigned)d.x >> SHIFT) * p.NQ + ((unsigned)s.x >> QSHIFT)], 1u);
        atomicAdd(&u.pt.hist[((unsigned)d.y >> SHIFT) * p.NQ + ((unsigned)s.y >> QSHIFT)], 1u);
        atomicAdd(&u.pt.hist[((unsigned)d.z >> SHIFT) * p.NQ + ((unsigned)s.z >> QSHIFT)], 1u);
        atomicAdd(&u.pt.hist[((unsigned)d.w >> SHIFT) * p.NQ + ((unsigned)s.w >> QSHIFT)], 1u);
      }
      __syncthreads();
      unsigned l[4]; unsigned s = 0;
      for (int k = 0; k < K; ++k) {
        int c = tid * K + k;
        unsigned v = (c < p.NCELL) ? u.pt.hist[c] : 0u;
        l[k] = s; s += v;
      }
      u.pt.ssum[tid] = s;
      __syncthreads();
      for (int ofs = 1; ofs < 256; ofs <<= 1) {
        unsigned v = (tid >= ofs) ? u.pt.ssum[tid - ofs] : 0u;
        __syncthreads();
        u.pt.ssum[tid] += v;
        __syncthreads();
      }
      unsigned excl = u.pt.ssum[tid] - s;
      for (int k = 0; k < K; ++k) {
        int c = tid * K + k;
        if (c < p.NCELL) {
          unsigned e = excl + l[k];
          u.pt.off[c] = e; u.pt.tscan[c] = e;
          u.pt.tbase[c] = u.pt.blkcur[c];
          u.pt.blkcur[c] += u.pt.hist[c];
        }
      }
      __syncthreads();
      for (int jj = tid; jj < tcnt; jj += 256) {
        int4 d = d4[t0 + jj]; int4 s2 = s4[t0 + jj];
#define STG1(dd, ss) { unsigned ud = (unsigned)(dd), us = (unsigned)(ss); \
        unsigned cell = (ud >> SHIFT) * p.NQ + (us >> QSHIFT); \
        unsigned pos = atomicAdd(&u.pt.off[cell], 1u); \
        u.pt.stage[pos] = (ud & MASK) | ((us & QMASK) << SHIFT); \
        u.pt.cellid[pos] = (unsigned short)cell; }
        STG1(d.x, s2.x) STG1(d.y, s2.y) STG1(d.z, s2.z) STG1(d.w, s2.w)
#undef STG1
      }
      __syncthreads();
      const int tc = 4 * tcnt;
      for (int i = tid; i < tc; i += 256) {
        unsigned c = u.pt.cellid[i];
        p.rec[u.pt.tbase[c] + ((unsigned)i - u.pt.tscan[c])] = u.pt.stage[i];
      }
    }
    __syncthreads();
    if (g == 0) {  // tail when E%4 != 0 (dead for E=6.4M)
      for (int t = p.e4 * 4 + tid; t < p.E; t += 256) {
        unsigned ud = (unsigned)p.dst[t], us = (unsigned)p.src[t];
        unsigned cell = (ud >> SHIFT) * p.NQ + (us >> QSHIFT);
        unsigned pos = atomicAdd(&u.pt.blkcur[cell], 1u);
        p.rec[pos] = (ud & MASK) | ((us & QMASK) << SHIFT);
      }
    }
  }
  grid.sync();

  // ===== Phase 5: degree from records (u16-packed bins) =====
  {
    for (int m = g; m < p.NB * DSJ; m += G) {
      const int pp = m / DSJ, j = m - pp * DSJ;
      for (int i = tid; i < RANGE / 2; i += 256) u.dg.bins[i] = 0u;
      __syncthreads();
      const int s0 = (int)p.cellst[pp * p.NQ], s1 = (int)p.cellst[(pp + 1) * p.NQ];
      const int len = s1 - s0;
      const int a = s0 + (int)((long)len * j / DSJ);
      const int b = s0 + (int)((long)len * (j + 1) / DSJ);
#define DEG1(v) { unsigned r = (v) & MASK; \
      atomicAdd(&u.dg.bins[r >> 1], 1u << ((r & 1) * 16)); }
      int i = a + tid;
      for (; i + 768 < b; i += 1024) {
        unsigned v0 = p.rec[i], v1 = p.rec[i + 256];
        unsigned v2 = p.rec[i + 512], v3 = p.rec[i + 768];
        DEG1(v0) DEG1(v1) DEG1(v2) DEG1(v3)
      }
      for (; i < b; i += 256) DEG1(p.rec[i])
#undef DEG1
      __syncthreads();
      unsigned* my32 = (unsigned*)(p.degpart + ((size_t)j * p.NB + pp) * RANGE);
      for (int i2 = tid; i2 < RANGE / 2; i2 += 256) my32[i2] = u.dg.bins[i2];
      __syncthreads();
    }
  }
  grid.sync();

  // ===== Phase 6: node1 (deg reduce -> dinv; dropout1 -> y) =====
  for (int i = g * 256 + tid; i < p.N; i += G * 256) {
    const int pp = i >> SHIFT, r = i & MASK;
    unsigned d = 0;
    for (int j = 0; j < DSJ; ++j)
      d += p.degpart[((size_t)j * p.NB + pp) * RANGE + r];
    float di = (d > 0) ? (1.0f / sqrtf((float)d)) : 0.0f;
    p.dinv[i] = di;
    unsigned o0, o1;
    threefry2x32(p.k1a, p.k1b, 0u, (unsigned)i, o0, o1);
    float uu = u01_from_bits(o0 ^ o1);
    float xd = (uu < KEEP_P) ? (p.x[i] / KEEP_P) : 0.0f;
    p.y[i] = xd * di;
  }
  grid.sync();

  // ===== Phase 7: scatter layer 1 =====
  scat_phase(p, u, p.y);
  grid.sync();

  // ===== Phase 8: node2 (s reduce; relu+dropout2+W2 dot -> z2) =====
  for (int i = g * 256 + tid; i < p.N; i += G * 256) {
    const int pp = i >> SHIFT, r = i & MASK;
    float s = 0.0f;
    for (int q = 0; q < p.NQ; ++q) {
      int mb = q * 2 * p.NB + (pp << 1);
      s += p.part[(size_t)mb * RANGE + r] + p.part[(size_t)(mb + 1) * RANGE + r];
    }
    float t = s * p.dinv[i];
    float z = 0.0f;
    unsigned base = (unsigned)i * 16u;
#pragma unroll
    for (int c = 0; c < 16; ++c) {
      float h = p.W1[c] * t + p.b1[c];
      h = fmaxf(h, 0.0f);
      unsigned o0, o1;
      threefry2x32(p.k2a, p.k2b, 0u, base + (unsigned)c, o0, o1);
      float uu = u01_from_bits(o0 ^ o1);
      float hd = (uu < KEEP_P) ? (h / KEEP_P) : 0.0f;
      z += hd * p.W2[c];
    }
    p.z2[i] = z * p.dinv[i];   // dinv[dst] applied in final phase
  }
  grid.sync();

  // ===== Phase 9: scatter layer 2 =====
  scat_phase(p, u, p.z2);
  grid.sync();

  // ===== Phase 10: final combine =====
  for (int i = g * 256 + tid; i < p.N; i += G * 256) {
    const int pp = i >> SHIFT, r = i & MASK;
    float s = 0.0f;
    for (int q = 0; q < p.NQ; ++q) {
      int mb = q * 2 * p.NB + (pp << 1);
      s += p.part[(size_t)mb * RANGE + r] + p.part[(size_t)(mb + 1) * RANGE + r];
    }
    p.out[i] = p.b2[0] + p.dinv[i] * s;
  }
}

extern "C" void kernel_launch(void* const* d_in, const int* in_sizes, int n_in,
                              void* d_out, int out_size, void* d_ws, size_t ws_size,
                              hipStream_t stream) {
  Par p;
  p.x  = (const float*)d_in[0];
  const int* edge = (const int*)d_in[1];   // [2, E] int32
  p.W1 = (const float*)d_in[2];
  p.b1 = (const float*)d_in[3];
  p.W2 = (const float*)d_in[4];
  p.b2 = (const float*)d_in[5];
  p.out = (float*)d_out;

  p.N = in_sizes[0];
  p.E = in_sizes[1] / 2;
  p.src = edge;
  p.dst = edge + p.E;
  p.e4 = p.E >> 2;
  p.NB = (p.N + RANGE - 1) / RANGE;    // 49 for N=100K
  p.NQ = (p.N + QRANGE - 1) / QRANGE;  // 13 for N=100K
  p.NCELL = p.NB * p.NQ;               // 637 <= NCELLP

  const int NP = (p.N + 255) & ~255;

  // ws: counts[NCELL*GMAX], bases[NCELL*GMAX], total, cellst, rec[E],
  //     part[2*NCELL*RANGE] f32 (aliases degpart), dinv, y, z2
  char* w = (char*)d_ws;
  auto align256 = [](char* q) {
    return (char*)(((uintptr_t)q + 255) & ~(uintptr_t)255);
  };
  p.counts = (unsigned*)w;  w = align256(w + (size_t)p.NCELL * GMAX * 4);
  p.bases  = (unsigned*)w;  w = align256(w + (size_t)p.NCELL * GMAX * 4);
  p.total  = (unsigned*)w;  w = align256(w + (size_t)p.NCELL * 4);
  p.cellst = (unsigned*)w;  w = align256(w + (size_t)(p.NCELL + 1) * 4);
  p.rec    = (unsigned*)w;  w = align256(w + (size_t)p.E * 4);
  p.part   = (float*)w;
  p.degpart = (unsigned short*)w;  // aliased: deg/node1 finish before scat1
  size_t part_bytes = (size_t)2 * p.NCELL * RANGE * 4;
  size_t deg_bytes  = (size_t)DSJ * p.NB * RANGE * 2;
  w = align256(w + (part_bytes > deg_bytes ? part_bytes : deg_bytes));
  p.dinv = (float*)w;
  p.y    = p.dinv + NP;
  p.z2   = p.y + NP;

  // Dropout keys: foldlike split(key(42)) under partitionable threefry.
  threefry2x32(0u, 42u, 0u, 0u, p.k1a, p.k1b);
  threefry2x32(0u, 42u, 0u, 1u, p.k2a, p.k2b);

  // Cooperative grid: all blocks co-resident (LDS ~62 KB -> 2 blocks/CU).
  int dev = 0;
  hipGetDevice(&dev);
  int numCU = 256;
  hipDeviceGetAttribute(&numCU, hipDeviceAttributeMultiprocessorCount, dev);
  int maxPerCU = 0;
  if (hipOccupancyMaxActiveBlocksPerMultiprocessor(&maxPerCU, k_all, 256, 0)
          != hipSuccess || maxPerCU < 1)
    maxPerCU = 1;
  int G = maxPerCU * numCU;
  if (G > GMAX) G = GMAX;
  if (G < 1) G = 1;

  void* args[] = { &p };
  hipLaunchCooperativeKernel(k_all, dim3(G), dim3(256), args, 0, stream);
}